// Round 4
// baseline (249.675 us; speedup 1.0000x reference)
//
#include <hip/hip_runtime.h>

// x: [16,128,128,128] fp32 ; pixel_shuffle(2) -> [16,32,256,256]
// 4x4 separable FIR (outer([1,3,3,1])/64), pad=2 -> out [16,32,257,257]
//
// R5: LDS-staged stencil, 1 thread = 1 output column. 112 -> 92us.
//   - per row: stage 256 dwords to LDS, coalesced 4B/lane
//   - E/O split LDS (2-way aliasing only, ~free per m136)
//   - vertical 4-tap via rolling regs; stores lane-consecutive
//   - 512 bc x 4 strips = 2048 blocks = 8/CU; VGPR 28, LDS 2.1KB
//
// R6: kill the barrier vmcnt drain. rocprof showed 3250 cy/iter-round vs
// ~1800 needed (HBM 1160 + VALU + LDS): __syncthreads() compiles to
// s_waitcnt vmcnt(0) lgkmcnt(0) + s_barrier, which DRAINED the 4-deep
// register prefetch ring every iteration — each of 68 rows paid full
// L2/HBM load latency serially at the barrier. Replace with single-asm
// "s_waitcnt lgkmcnt(0); s_barrier" (AITER pattern: loads stay in flight
// across barriers; compiler emits counted vmcnt(N) at the ds_write that
// consumes rr). LDS cross-wave ordering still guaranteed by lgkmcnt(0).
// Single asm block + memory clobber so no compiler wait lands in between.
constexpr int Hn = 128;
constexpr int Wn = 128;
constexpr int SH = 2 * Hn;   // 256 shuffled rows
constexpr int OH = SH + 1;   // 257
constexpr int OW = 257;
constexpr int HW = Hn * Wn;  // input plane stride
constexpr int TY = 65;       // output rows per block
constexpr int NSTRIP = 4;    // 4*65 = 260 >= 257
constexpr int NBC = 16 * 32; // 512 (b,c) planes
constexpr int PF = 4;        // prefetch depth (rows in flight)
constexpr int NIT = TY + 3;  // 68 staged rows per strip

// Barrier that does NOT drain vmem: LDS ordering only.
__device__ __forceinline__ void barrier_lgkm_only() {
    asm volatile("s_waitcnt lgkmcnt(0)\n\ts_barrier" ::: "memory");
}

__global__ __launch_bounds__(256, 8) void upsamp_fir_lds(
    const float* __restrict__ x,
    const float* __restrict__ k4,
    float* __restrict__ out)
{
    const int tix = threadIdx.x;
    const int bc  = blockIdx.x;
    const int oh0 = blockIdx.y * TY;
    const float* xp = x + (size_t)bc * 4 * HW;

    // Separable taps (flipped for true convolution), exact for this kernel.
    float fh[4], fv[4];
#pragma unroll
    for (int j = 0; j < 4; ++j) fh[j] = k4[j] + k4[4+j] + k4[8+j] + k4[12+j];
#pragma unroll
    for (int i = 0; i < 4; ++i) fv[i] = k4[4*i] + k4[4*i+1] + k4[4*i+2] + k4[4*i+3];
    const float h0 = fh[3], h1 = fh[2], h2 = fh[1], h3 = fh[0];
    const float g0 = fv[3], g1 = fv[2], g2 = fv[1], g3 = fv[0];

    // LDS: [buf][E/O][132]. EB[1+j] = shuffled col 2j, OB[1+j] = col 2j+1.
    // EB[0]/OB[0] = cols -2/-1 (zero), EB[129]/OB[129] = cols 256/257 (zero).
    __shared__ float lds[2][2][132];
    if (tix < 8) {
        int b = tix >> 2, r = tix & 3;
        lds[b][r >> 1][(r & 1) ? 129 : 0] = 0.f;
    }

    // Staging role: threads 0..127 load even plane dword (tix), 128..255 odd.
    const int eo       = tix < 128 ? 0 : 1;
    const int lane     = tix & 127;
    const int stageIdx = 1 + lane;

    auto xload = [&](int s) -> float {
        // shuffled row s: planes 2*(s&1) (+1 for odd cols), input row s>>1
        return xp[(size_t)(2 * (s & 1) + eo) * HW + (size_t)(s >> 1) * Wn + lane];
    };

    // Output column owned by this thread (plus col 256 for tix==255).
    const int c    = tix;
    const int mi   = c >> 1;
    const int codd = c & 1;
    const bool edge = (tix == 255);

    float* const obase = out + (size_t)bc * OH * OW;

    // Prologue: rows oh0-2 .. oh0+1 into the 4-slot ring.
    float rr0 = 0, rr1 = 0, rr2 = 0, rr3 = 0;
    { int s = oh0 - 2; if ((unsigned)s < (unsigned)SH) rr0 = xload(s); }
    { int s = oh0 - 1; if ((unsigned)s < (unsigned)SH) rr1 = xload(s); }
    { int s = oh0;     if ((unsigned)s < (unsigned)SH) rr2 = xload(s); }
    { int s = oh0 + 1; if ((unsigned)s < (unsigned)SH) rr3 = xload(s); }

    // Rolling horizontal-FIR rows: hm1 = h(s-1), hm2 = h(s-2), hm3 = h(s-3).
    float hm3 = 0, hm2 = 0, hm1 = 0;
    float em3 = 0, em2 = 0, em1 = 0;   // same, for col 256 (edge thread)

    auto step = [&](int m, float& rr, int buf) {
        const int s = oh0 - 2 + m;          // shuffled row staged this iter
        // Stage current row (value prefetched PF iters ago; 0 if OOB).
        // Compiler inserts a COUNTED s_waitcnt vmcnt(N) here for rr.
        lds[buf][eo][stageIdx] = rr;
        // Prefetch row s+PF into the freed ring slot.
        float nv = 0.f;
        const int sp = s + PF;
        if (m < NIT - PF && sp < SH) nv = xload(sp);
        rr = nv;
        barrier_lgkm_only();                // NO vmcnt drain: prefetch lives on
        // Horizontal FIR at col c: window cols c-2..c+1 via E/O pair reads.
        const float* EB = lds[buf][0];
        const float* OB = lds[buf][1];
        // even c: reads EB[mi],OB[mi],EB[mi+1],OB[mi+1]
        // odd  c: reads OB[mi],EB[mi+1],OB[mi+1],EB[mi+2]
        const float* P = codd ? (OB + mi) : (EB + mi);
        const float* Q = codd ? (EB + mi + 1) : (OB + mi);
        const float p0 = P[0], p1 = P[1];   // -> ds_read2_b32
        const float q0 = Q[0], q1 = Q[1];   // -> ds_read2_b32
        const float hn = h0*p0 + h1*q0 + h2*p1 + h3*q1;
        float en = 0.f;
        if (edge) {                          // col 256: EB[129]/OB[129] are 0
            en = h0*EB[128] + h1*OB[128] + h2*EB[129] + h3*OB[129];
        }
        // Emit output row oh = s-1 (needs h rows s-3..s).
        if (m >= 3) {
            const int oh = oh0 + m - 3;
            if (oh < OH) {
                float* p = obase + (size_t)oh * OW;
                p[c] = g0*hm3 + g1*hm2 + g2*hm1 + g3*hn;   // coalesced
                if (edge) p[256] = g0*em3 + g1*em2 + g2*em1 + g3*en;
            }
        }
        hm3 = hm2; hm2 = hm1; hm1 = hn;
        em3 = em2; em2 = em1; em1 = en;
    };

    // NIT=68 iterations; unrolled by 4 so ring slots & buffers are static
    // (rule: runtime-indexed register arrays spill to scratch).
    for (int mm = 0; mm < NIT; mm += 4) {
        step(mm + 0, rr0, 0);
        step(mm + 1, rr1, 1);
        step(mm + 2, rr2, 0);
        step(mm + 3, rr3, 1);
    }
}

extern "C" void kernel_launch(void* const* d_in, const int* in_sizes, int n_in,
                              void* d_out, int out_size, void* d_ws, size_t ws_size,
                              hipStream_t stream)
{
    const float* x  = (const float*)d_in[0];
    const float* k4 = (const float*)d_in[1];
    float* out      = (float*)d_out;

    dim3 grid(NBC, NSTRIP, 1);
    upsamp_fir_lds<<<grid, dim3(256), 0, stream>>>(x, k4, out);
}